// Round 2
// baseline (3557.082 us; speedup 1.0000x reference)
//
#include <hip/hip_runtime.h>
#include <math.h>

// Problem dims
#define NLAYERS 8
#define BATCH   4
#define SEQ     2048
#define DIM     256
#define SDIM    512
#define MROWS   (BATCH*SEQ)   // 8192
#define K1      (2*DIM)       // 512
#define N1      2048          // [Bx_r 512 | Bx_i 512 | gate 512 | Dx_r 256 | Dx_i 256]
#define K2      (2*SDIM)      // 1024
#define N2      (2*DIM)       // 512 (r/i interleaved per dim)
#define SCH     16            // scan chunks
#define SCL     (SEQ/SCH)     // 128 steps per chunk

// ---------------------------------------------------------------------------
// LayerNorm over D per (b,s), real/imag independently.
__global__ __launch_bounds__(256) void ln_kernel(
    const float* __restrict__ x, const float* __restrict__ gamma,
    const float* __restrict__ beta, float* __restrict__ out, int split_out)
{
    int row = blockIdx.x;          // b*SEQ + s
    int d = threadIdx.x;           // 0..255
    const float2* xp = (const float2*)(x + (size_t)row * DIM * 2);
    float2 v = xp[d];
    float xr = v.x, xi = v.y;

    __shared__ float4 red[256];
    red[d] = make_float4(xr, xi, xr * xr, xi * xi);
    __syncthreads();
    for (int s = 128; s > 0; s >>= 1) {
        if (d < s) {
            float4 a = red[d], b4 = red[d + s];
            red[d] = make_float4(a.x + b4.x, a.y + b4.y, a.z + b4.z, a.w + b4.w);
        }
        __syncthreads();
    }
    float4 tot = red[0];
    float mur = tot.x * (1.0f / DIM), mui = tot.y * (1.0f / DIM);
    float varr = tot.z * (1.0f / DIM) - mur * mur;
    float vari = tot.w * (1.0f / DIM) - mui * mui;
    float rr = rsqrtf(varr + 1e-5f), ri = rsqrtf(vari + 1e-5f);
    float g = gamma[d], b = beta[d];
    float yr = (xr - mur) * rr * g + b;
    float yi = (xi - mui) * ri * g + b;
    if (split_out) {
        out[(size_t)row * K1 + d] = yr;
        out[(size_t)row * K1 + DIM + d] = yi;
    } else {
        float2* op = (float2*)(out + (size_t)row * DIM * 2);
        op[d] = make_float2(yr, yi);
    }
}

// ---------------------------------------------------------------------------
// Build W1 [512 x 2048]: cols [BWr/-BWi | BWi/BWr | gW | DWr/-DWi | DWi/DWr]
__global__ __launch_bounds__(256) void prep_w1(
    const float* __restrict__ BWr, const float* __restrict__ BWi,
    const float* __restrict__ gW, const float* __restrict__ DWr,
    const float* __restrict__ DWi, float* __restrict__ W1)
{
    int idx = blockIdx.x * 256 + threadIdx.x;   // < 512*2048
    int k = idx >> 11;
    int n = idx & 2047;
    float v;
    if (n < 1024) {
        bool ip = n >= 512; int nn = ip ? n - 512 : n;
        if (k < 256) v = ip ? BWi[k * SDIM + nn] : BWr[k * SDIM + nn];
        else { int kp = k - 256; v = ip ? BWr[kp * SDIM + nn] : -BWi[kp * SDIM + nn]; }
    } else if (n < 1536) {
        v = gW[(size_t)k * SDIM + (n - 1024)];   // gate_W is [2D=512, SD]
    } else {
        bool ip = n >= 1792; int nn = ip ? n - 1792 : n - 1536;
        if (k < 256) v = ip ? DWi[k * DIM + nn] : DWr[k * DIM + nn];
        else { int kp = k - 256; v = ip ? DWr[kp * DIM + nn] : -DWi[kp * DIM + nn]; }
    }
    W1[idx] = v;
}

// Build W2 [1024 x 512], col 2d=y_r coefs, 2d+1=y_i coefs
__global__ __launch_bounds__(256) void prep_w2(
    const float* __restrict__ CWr, const float* __restrict__ CWi, float* __restrict__ W2)
{
    int idx = blockIdx.x * 256 + threadIdx.x;   // < 1024*512
    int k = idx >> 9;
    int n = idx & 511;
    int d = n >> 1, c = n & 1;
    float v;
    if (k < 512) v = c ? CWi[k * DIM + d] : CWr[k * DIM + d];
    else { int kp = k - 512; v = c ? CWr[kp * DIM + d] : -CWi[kp * DIM + d]; }
    W2[idx] = v;
}

// ---------------------------------------------------------------------------
// Tiled f32 GEMM: C[M,N] = A[M,K] @ W[K,N]. BM=BN=64, BK=16, 256 thr, 4x4/thr.
template <int MODE>
__global__ __launch_bounds__(256) void gemm_kernel(
    const float* __restrict__ A, const float* __restrict__ W,
    float* __restrict__ Cout, int Kdim, int Ndim,
    const float* __restrict__ gbias, const float* __restrict__ dx_src,
    float* __restrict__ hio)
{
    constexpr int BM = 64, BN = 64, BK = 16;
    __shared__ float As[BK][BM];
    __shared__ float Bs[BK][BN];
    int tid = threadIdx.x;
    int row0 = blockIdx.y * BM;
    int col0 = blockIdx.x * BN;
    int tx = tid & 15, ty = tid >> 4;

    int am = tid >> 2;             // 0..63
    int ak = (tid & 3) << 2;       // 0,4,8,12
    int bk = tid >> 4;             // 0..15
    int bn = (tid & 15) << 2;      // 0..60

    float acc[4][4] = {};

    for (int k0 = 0; k0 < Kdim; k0 += BK) {
        float4 av = *(const float4*)(A + (size_t)(row0 + am) * Kdim + k0 + ak);
        float4 bv = *(const float4*)(W + (size_t)(k0 + bk) * Ndim + col0 + bn);
        As[ak + 0][am] = av.x;
        As[ak + 1][am] = av.y;
        As[ak + 2][am] = av.z;
        As[ak + 3][am] = av.w;
        *(float4*)&Bs[bk][bn] = bv;
        __syncthreads();
#pragma unroll
        for (int kk = 0; kk < BK; ++kk) {
            float a0 = As[kk][ty * 4 + 0], a1 = As[kk][ty * 4 + 1];
            float a2 = As[kk][ty * 4 + 2], a3 = As[kk][ty * 4 + 3];
            float b0 = Bs[kk][tx * 4 + 0], b1 = Bs[kk][tx * 4 + 1];
            float b2 = Bs[kk][tx * 4 + 2], b3 = Bs[kk][tx * 4 + 3];
            acc[0][0] += a0 * b0; acc[0][1] += a0 * b1; acc[0][2] += a0 * b2; acc[0][3] += a0 * b3;
            acc[1][0] += a1 * b0; acc[1][1] += a1 * b1; acc[1][2] += a1 * b2; acc[1][3] += a1 * b3;
            acc[2][0] += a2 * b0; acc[2][1] += a2 * b1; acc[2][2] += a2 * b2; acc[2][3] += a2 * b3;
            acc[3][0] += a3 * b0; acc[3][1] += a3 * b1; acc[3][2] += a3 * b2; acc[3][3] += a3 * b3;
        }
        __syncthreads();
    }

    if (MODE == 0) {
#pragma unroll
        for (int i = 0; i < 4; ++i) {
            int m = row0 + ty * 4 + i;
#pragma unroll
            for (int j = 0; j < 4; ++j) {
                int c = col0 + tx * 4 + j;
                float v = acc[i][j];
                if (c >= 1024 && c < 1536)
                    v = 1.0f / (1.0f + expf(-(v + gbias[c - 1024])));
                Cout[(size_t)m * Ndim + c] = v;
            }
        }
    } else {
#pragma unroll
        for (int i = 0; i < 4; ++i) {
            int m = row0 + ty * 4 + i;
#pragma unroll
            for (int jp = 0; jp < 4; jp += 2) {
                int c0 = col0 + tx * 4 + jp;     // even col = real
                int d = c0 >> 1;
                float yr = acc[i][jp]     + dx_src[(size_t)m * N1 + 1536 + d];
                float yi = acc[i][jp + 1] + dx_src[(size_t)m * N1 + 1792 + d];
                float outr = yr * yr + yr;
                float outi = yr * yi + yi;
                size_t idx = (size_t)m * 512 + c0;
                hio[idx]     += 0.1f * outr;
                hio[idx + 1] += 0.1f * outi;
            }
        }
    }
}

// ---------------------------------------------------------------------------
// Chunked scan, phase 1: per (b, chunk, n) compute affine map h_out = P*h_in + q
// over the chunk.  a_t = (1-g_t)*damp*e^{i theta},  b_t = g_t*Bx_t.
// Pq layout: float4 {Pr,Pi,qr,qi} at [(b*SCH+c)*SDIM + n].
__global__ __launch_bounds__(256) void scan1_kernel(
    const float* __restrict__ g1out, const float* __restrict__ theta,
    const float* __restrict__ damp_p, float4* __restrict__ Pq)
{
    int idx = blockIdx.x * 256 + threadIdx.x;      // < BATCH*SCH*SDIM
    int n = idx & (SDIM - 1);
    int c = (idx >> 9) & (SCH - 1);
    int b = idx >> 13;
    float th = theta[n];
    float dp = 0.5f + 0.5f * (1.0f / (1.0f + expf(-damp_p[n])));
    float cr = dp * cosf(th), ci = dp * sinf(th);

    const float* rbase = g1out + ((size_t)b * SEQ + (size_t)c * SCL) * N1;
    float Pr = 1.0f, Pi = 0.0f, qr = 0.0f, qi = 0.0f;
    for (int t = 0; t < SCL; ++t) {
        const float* rp = rbase + (size_t)t * N1;
        float g = rp[1024 + n], br = rp[n], bi = rp[512 + n];
        float ar = (1.0f - g) * cr, ai = (1.0f - g) * ci;
        // q = a*q + g*bx ; P = a*P
        float nqr = ar * qr - ai * qi + g * br;
        float nqi = ar * qi + ai * qr + g * bi;
        float nPr = ar * Pr - ai * Pi;
        float nPi = ar * Pi + ai * Pr;
        qr = nqr; qi = nqi; Pr = nPr; Pi = nPi;
    }
    Pq[idx] = make_float4(Pr, Pi, qr, qi);
}

// Phase 2: sequential combine over chunks per channel; emits per-chunk input
// state hin[(b*SCH+c)*SDIM+n] (float2) and final hidden state.
__global__ __launch_bounds__(256) void scan2_kernel(
    const float4* __restrict__ Pq, const float* __restrict__ h0,
    float2* __restrict__ hin, float* __restrict__ hfin)
{
    int idx = blockIdx.x * 256 + threadIdx.x;      // < BATCH*SDIM
    int n = idx & (SDIM - 1);
    int b = idx >> 9;
    float hr = h0[idx * 2], hi = h0[idx * 2 + 1];
    for (int c = 0; c < SCH; ++c) {
        int o = (b * SCH + c) * SDIM + n;
        hin[o] = make_float2(hr, hi);
        float4 pq = Pq[o];
        float nr = pq.x * hr - pq.y * hi + pq.z;
        float ni = pq.x * hi + pq.y * hr + pq.w;
        hr = nr; hi = ni;
    }
    hfin[idx * 2] = hr;
    hfin[idx * 2 + 1] = hi;
}

// Phase 3: replay each chunk from its known input state, writing h_all.
__global__ __launch_bounds__(256) void scan3_kernel(
    const float* __restrict__ g1out, const float* __restrict__ theta,
    const float* __restrict__ damp_p, const float2* __restrict__ hin,
    float* __restrict__ h_all)
{
    int idx = blockIdx.x * 256 + threadIdx.x;      // < BATCH*SCH*SDIM
    int n = idx & (SDIM - 1);
    int c = (idx >> 9) & (SCH - 1);
    int b = idx >> 13;
    float th = theta[n];
    float dp = 0.5f + 0.5f * (1.0f / (1.0f + expf(-damp_p[n])));
    float cr = dp * cosf(th), ci = dp * sinf(th);

    float2 h = hin[idx];
    float hr = h.x, hi = h.y;
    const float* rbase = g1out + ((size_t)b * SEQ + (size_t)c * SCL) * N1;
    float* hbase = h_all + ((size_t)b * SEQ + (size_t)c * SCL) * K2;
    for (int t = 0; t < SCL; ++t) {
        const float* rp = rbase + (size_t)t * N1;
        float g = rp[1024 + n], br = rp[n], bi = rp[512 + n];
        float omg = 1.0f - g;
        float nr = g * br + omg * (hr * cr - hi * ci);
        float ni = g * bi + omg * (hr * ci + hi * cr);
        hr = nr; hi = ni;
        hbase[(size_t)t * K2 + n] = hr;
        hbase[(size_t)t * K2 + SDIM + n] = hi;
    }
}

// ---------------------------------------------------------------------------
extern "C" void kernel_launch(void* const* d_in, const int* in_sizes, int n_in,
                              void* d_out, int out_size, void* d_ws, size_t ws_size,
                              hipStream_t stream)
{
    const float* x     = (const float*)d_in[0];
    const float* h0    = (const float*)d_in[1];
    const float* theta = (const float*)d_in[2];
    const float* dampp = (const float*)d_in[3];
    const float* BWr   = (const float*)d_in[4];
    const float* BWi   = (const float*)d_in[5];
    const float* CWr   = (const float*)d_in[6];
    const float* CWi   = (const float*)d_in[7];
    const float* DWr   = (const float*)d_in[8];
    const float* DWi   = (const float*)d_in[9];
    const float* gW    = (const float*)d_in[10];
    const float* gb    = (const float*)d_in[11];
    const float* ng    = (const float*)d_in[12];
    const float* nb    = (const float*)d_in[13];
    const float* og    = (const float*)d_in[14];
    const float* ob    = (const float*)d_in[15];
    float* out = (float*)d_out;

    float* ws   = (float*)d_ws;
    float* hbuf = ws;                                   // 4,194,304 f
    float* xn   = hbuf + (size_t)MROWS * DIM * 2;       // 4,194,304 f
    float* g1o  = xn   + (size_t)MROWS * K1;            // 16,777,216 f
    float* hall = g1o  + (size_t)MROWS * N1;            // 8,388,608 f
    float* W1   = hall + (size_t)MROWS * K2;            // 1,048,576 f
    float* W2   = W1   + (size_t)K1 * N1;               //   524,288 f
    float4* Pq  = (float4*)(W2 + (size_t)K2 * N2);      // 32,768 float4
    float2* hin = (float2*)(W2 + (size_t)K2 * N2 + 4 * BATCH * SCH * SDIM);

    hipMemcpyAsync(hbuf, x, (size_t)MROWS * DIM * 2 * sizeof(float),
                   hipMemcpyDeviceToDevice, stream);

    for (int l = 0; l < NLAYERS; ++l) {
        ln_kernel<<<MROWS, 256, 0, stream>>>(hbuf, ng + l * DIM, nb + l * DIM, xn, 1);
        prep_w1<<<(K1 * N1) / 256, 256, 0, stream>>>(
            BWr + (size_t)l * DIM * SDIM, BWi + (size_t)l * DIM * SDIM,
            gW + (size_t)l * K1 * SDIM,
            DWr + (size_t)l * DIM * DIM, DWi + (size_t)l * DIM * DIM, W1);
        prep_w2<<<(K2 * N2) / 256, 256, 0, stream>>>(
            CWr + (size_t)l * SDIM * DIM, CWi + (size_t)l * SDIM * DIM, W2);

        dim3 g1grid(N1 / 64, MROWS / 64);
        gemm_kernel<0><<<g1grid, 256, 0, stream>>>(xn, W1, g1o, K1, N1,
                                                   gb + l * SDIM, nullptr, nullptr);

        scan1_kernel<<<(BATCH * SCH * SDIM) / 256, 256, 0, stream>>>(
            g1o, theta + l * SDIM, dampp + l * SDIM, Pq);
        scan2_kernel<<<(BATCH * SDIM) / 256, 256, 0, stream>>>(
            Pq, h0 + (size_t)l * BATCH * SDIM * 2, hin,
            out + (size_t)MROWS * DIM * 2 + (size_t)l * BATCH * SDIM * 2);
        scan3_kernel<<<(BATCH * SCH * SDIM) / 256, 256, 0, stream>>>(
            g1o, theta + l * SDIM, dampp + l * SDIM, hin, hall);

        dim3 g2grid(N2 / 64, MROWS / 64);
        gemm_kernel<1><<<g2grid, 256, 0, stream>>>(hall, W2, nullptr, K2, N2,
                                                   nullptr, g1o, hbuf);
    }
    ln_kernel<<<MROWS, 256, 0, stream>>>(hbuf, og, ob, out, 0);
}

// Round 3
// 1001.096 us; speedup vs baseline: 3.5532x; 3.5532x over previous
//
#include <hip/hip_runtime.h>
#include <math.h>

// Problem dims
#define NLAYERS 8
#define BATCH   4
#define SEQ     2048
#define DIM     256
#define SDIM    512
#define MROWS   (BATCH*SEQ)   // 8192
#define K1      (2*DIM)       // 512
#define N1      2048          // [Bx_r 512 | Bx_i 512 | gate 512 | Dx_r 256 | Dx_i 256]
#define K2      (2*SDIM)      // 1024
#define N2      (2*DIM)       // 512 (r/i interleaved per dim)
#define SCH     64            // scan chunks
#define SCH_LOG 6
#define SCL     (SEQ/SCH)     // 32 steps per chunk

typedef __attribute__((ext_vector_type(8))) short bf16x8;
typedef __attribute__((ext_vector_type(4))) float f32x4;

__device__ __forceinline__ unsigned short f2bf(float f) {
    union { float f; unsigned u; } v; v.f = f;
    unsigned r = (v.u + 0x7FFF + ((v.u >> 16) & 1)) >> 16;
    return (unsigned short)r;
}
__device__ __forceinline__ float bf2f(unsigned short s) {
    union { unsigned u; float f; } v; v.u = ((unsigned)s) << 16;
    return v.f;
}

__device__ __forceinline__ void gload_lds16(const void* g, void* l) {
    __builtin_amdgcn_global_load_lds(
        (const __attribute__((address_space(1))) void*)g,
        (__attribute__((address_space(3))) void*)l, 16, 0, 0);
}

// ---------------------------------------------------------------------------
// LayerNorm over D, real/imag independently.
// mode 1: write bf16 split [row][xr(256)|xi(256)]; mode 0: write f32 interleaved
__global__ __launch_bounds__(256) void ln_kernel(
    const float* __restrict__ x, const float* __restrict__ gamma,
    const float* __restrict__ beta, unsigned short* __restrict__ outb,
    float* __restrict__ outf, int mode)
{
    int row = blockIdx.x;
    int d = threadIdx.x;
    const float2* xp = (const float2*)(x + (size_t)row * DIM * 2);
    float2 v = xp[d];
    float xr = v.x, xi = v.y;

    __shared__ float4 red[256];
    red[d] = make_float4(xr, xi, xr * xr, xi * xi);
    __syncthreads();
    for (int s = 128; s > 0; s >>= 1) {
        if (d < s) {
            float4 a = red[d], b4 = red[d + s];
            red[d] = make_float4(a.x + b4.x, a.y + b4.y, a.z + b4.z, a.w + b4.w);
        }
        __syncthreads();
    }
    float4 tot = red[0];
    float mur = tot.x * (1.0f / DIM), mui = tot.y * (1.0f / DIM);
    float varr = tot.z * (1.0f / DIM) - mur * mur;
    float vari = tot.w * (1.0f / DIM) - mui * mui;
    float rr = rsqrtf(varr + 1e-5f), ri = rsqrtf(vari + 1e-5f);
    float g = gamma[d], b = beta[d];
    float yr = (xr - mur) * rr * g + b;
    float yi = (xi - mui) * ri * g + b;
    if (mode) {
        outb[(size_t)row * K1 + d] = f2bf(yr);
        outb[(size_t)row * K1 + DIM + d] = f2bf(yi);
    } else {
        float2* op = (float2*)(outf + (size_t)row * DIM * 2);
        op[d] = make_float2(yr, yi);
    }
}

// ---------------------------------------------------------------------------
__device__ __forceinline__ float w1_val(int k, int n,
    const float* __restrict__ BWr, const float* __restrict__ BWi,
    const float* __restrict__ gW, const float* __restrict__ DWr,
    const float* __restrict__ DWi)
{
    if (n < 1024) {
        bool ip = n >= 512; int nn = ip ? n - 512 : n;
        if (k < 256) return ip ? BWi[k * SDIM + nn] : BWr[k * SDIM + nn];
        int kp = k - 256; return ip ? BWr[kp * SDIM + nn] : -BWi[kp * SDIM + nn];
    } else if (n < 1536) {
        return gW[(size_t)k * SDIM + (n - 1024)];
    } else {
        bool ip = n >= 1792; int nn = ip ? n - 1792 : n - 1536;
        if (k < 256) return ip ? DWi[k * DIM + nn] : DWr[k * DIM + nn];
        int kp = k - 256; return ip ? DWr[kp * DIM + nn] : -DWi[kp * DIM + nn];
    }
}

// W1t [N1=2048][K1=512] bf16, transposed via LDS tile. grid (64,16)
__global__ __launch_bounds__(256) void prep_w1t(
    const float* __restrict__ BWr, const float* __restrict__ BWi,
    const float* __restrict__ gW, const float* __restrict__ DWr,
    const float* __restrict__ DWi, unsigned short* __restrict__ W1t)
{
    __shared__ float tile[32][33];
    int tx = threadIdx.x & 31, ty = threadIdx.x >> 5;
    int nB = blockIdx.x * 32, kB = blockIdx.y * 32;
#pragma unroll
    for (int i = 0; i < 4; ++i)
        tile[ty + i * 8][tx] = w1_val(kB + ty + i * 8, nB + tx, BWr, BWi, gW, DWr, DWi);
    __syncthreads();
#pragma unroll
    for (int i = 0; i < 4; ++i)
        W1t[(size_t)(nB + ty + i * 8) * K1 + kB + tx] = f2bf(tile[tx][ty + i * 8]);
}

__device__ __forceinline__ float w2_val(int k, int n,
    const float* __restrict__ CWr, const float* __restrict__ CWi)
{
    int d = n >> 1, c = n & 1;
    if (k < 512) return c ? CWi[k * DIM + d] : CWr[k * DIM + d];
    int kp = k - 512; return c ? CWr[kp * DIM + d] : -CWi[kp * DIM + d];
}

// W2t [N2=512][K2=1024] bf16. grid (16,32)
__global__ __launch_bounds__(256) void prep_w2t(
    const float* __restrict__ CWr, const float* __restrict__ CWi,
    unsigned short* __restrict__ W2t)
{
    __shared__ float tile[32][33];
    int tx = threadIdx.x & 31, ty = threadIdx.x >> 5;
    int nB = blockIdx.x * 32, kB = blockIdx.y * 32;
#pragma unroll
    for (int i = 0; i < 4; ++i)
        tile[ty + i * 8][tx] = w2_val(kB + ty + i * 8, nB + tx, CWr, CWi);
    __syncthreads();
#pragma unroll
    for (int i = 0; i < 4; ++i)
        W2t[(size_t)(nB + ty + i * 8) * K2 + kB + tx] = f2bf(tile[tx][ty + i * 8]);
}

// ---------------------------------------------------------------------------
// bf16 MFMA GEMM, m97 structure: 128x128 tile, BK=32, 4 waves (2x2), 64x64/wave.
// A [M][K] bf16 row-major, Bt [N][K] bf16 row-major.
// MODE 0: Cout bf16 [M][2048], sigmoid on cols [1024,1536)
// MODE 1: y = acc + Dx(bf16 from dxsrc), out = yr*y+y, hio(f32 [M][512]) += 0.1*out
template <int MODE>
__global__ __launch_bounds__(256) void mfma_gemm(
    const unsigned short* __restrict__ A, const unsigned short* __restrict__ Bt,
    unsigned short* __restrict__ Cout, int K,
    const float* __restrict__ gbias, const unsigned short* __restrict__ dxsrc,
    float* __restrict__ hio)
{
    __shared__ __align__(16) unsigned short As[128 * 32];
    __shared__ __align__(16) unsigned short Bs[128 * 32];
    const int tid = threadIdx.x;
    const int lane = tid & 63;
    const int w = tid >> 6;
    const int wr = w >> 1, wc = w & 1;
    const int row0 = blockIdx.y * 128;
    const int col0 = blockIdx.x * 128;

    f32x4 acc[4][4];
#pragma unroll
    for (int i = 0; i < 4; ++i)
#pragma unroll
        for (int j = 0; j < 4; ++j) acc[i][j] = (f32x4)(0.0f);

    const int srow16 = lane >> 2;       // 0..15 (staging row within 16-row group)
    const int schunk = lane & 3;        // 16B chunk within 64B row
    const int frow = lane & 15;
    const int kgrp = lane >> 4;         // 0..3

    // fragment LDS offsets (shorts), chunk-XOR swizzled
    int aoff[4], boff[4];
#pragma unroll
    for (int i = 0; i < 4; ++i) {
        int ra = wr * 64 + i * 16 + frow;
        aoff[i] = ra * 32 + ((kgrp ^ ((ra >> 1) & 3)) * 8);
        int rb = wc * 64 + i * 16 + frow;
        boff[i] = rb * 32 + ((kgrp ^ ((rb >> 1) & 3)) * 8);
    }
    // staging rows (2 groups of 16 per wave), pre-swizzled global chunk
    int srA[2], sgc[2];
#pragma unroll
    for (int c = 0; c < 2; ++c) {
        srA[c] = w * 32 + c * 16 + srow16;
        sgc[c] = (schunk ^ ((srA[c] >> 1) & 3)) * 8;
    }

    for (int k0 = 0; k0 < K; k0 += 32) {
#pragma unroll
        for (int c = 0; c < 2; ++c) {
            gload_lds16(A + (size_t)(row0 + srA[c]) * K + k0 + sgc[c],
                        &As[(w * 32 + c * 16) * 32]);
            gload_lds16(Bt + (size_t)(col0 + srA[c]) * K + k0 + sgc[c],
                        &Bs[(w * 32 + c * 16) * 32]);
        }
        __syncthreads();   // drains vmcnt -> tiles visible
        bf16x8 aF[4], bF[4];
#pragma unroll
        for (int i = 0; i < 4; ++i) {
            aF[i] = *(const bf16x8*)&As[aoff[i]];
            bF[i] = *(const bf16x8*)&Bs[boff[i]];
        }
#pragma unroll
        for (int mi = 0; mi < 4; ++mi)
#pragma unroll
            for (int nj = 0; nj < 4; ++nj)
                acc[mi][nj] = __builtin_amdgcn_mfma_f32_16x16x32_bf16(
                    aF[mi], bF[nj], acc[mi][nj], 0, 0, 0);
        __syncthreads();   // all reads done before next stage overwrites
    }

    if (MODE == 0) {
#pragma unroll
        for (int mi = 0; mi < 4; ++mi) {
#pragma unroll
            for (int nj = 0; nj < 4; ++nj) {
                int c = col0 + wc * 64 + nj * 16 + frow;
                int mbase = row0 + wr * 64 + mi * 16 + kgrp * 4;
                bool isg = (c >= 1024 && c < 1536);
                float gb_ = isg ? gbias[c - 1024] : 0.0f;
#pragma unroll
                for (int r = 0; r < 4; ++r) {
                    float v = acc[mi][nj][r];
                    if (isg) v = 1.0f / (1.0f + expf(-(v + gb_)));
                    Cout[(size_t)(mbase + r) * 2048 + c] = f2bf(v);
                }
            }
        }
    } else {
#pragma unroll
        for (int mi = 0; mi < 4; ++mi) {
#pragma unroll
            for (int nj = 0; nj < 4; ++nj) {
                int c = col0 + wc * 64 + nj * 16 + frow;   // 0..511
                int d = c >> 1;
                int dxoff = (c & 1) ? (1792 + d) : (1536 + d);
                int mbase = row0 + wr * 64 + mi * 16 + kgrp * 4;
#pragma unroll
                for (int r = 0; r < 4; ++r) {
                    int m = mbase + r;
                    float y = acc[mi][nj][r] + bf2f(dxsrc[(size_t)m * 2048 + dxoff]);
                    float yo = __shfl_xor(y, 1);
                    float yr = (c & 1) ? yo : y;
                    float o = yr * y + y;
                    hio[(size_t)m * 512 + c] += 0.1f * o;
                }
            }
        }
    }
}

// ---------------------------------------------------------------------------
// Chunked scan on bf16 g1o [row][2048]: phase 1 affine maps
__global__ __launch_bounds__(256) void scan1_kernel(
    const unsigned short* __restrict__ g1o, const float* __restrict__ theta,
    const float* __restrict__ damp_p, float4* __restrict__ Pq)
{
    int idx = blockIdx.x * 256 + threadIdx.x;      // < BATCH*SCH*SDIM
    int n = idx & (SDIM - 1);
    int c = (idx >> 9) & (SCH - 1);
    int b = idx >> (9 + SCH_LOG);
    float th = theta[n];
    float dp = 0.5f + 0.5f * (1.0f / (1.0f + expf(-damp_p[n])));
    float cr = dp * cosf(th), ci = dp * sinf(th);

    const unsigned short* rbase = g1o + ((size_t)b * SEQ + (size_t)c * SCL) * N1;
    float Pr = 1.0f, Pi = 0.0f, qr = 0.0f, qi = 0.0f;
#pragma unroll 4
    for (int t = 0; t < SCL; ++t) {
        const unsigned short* rp = rbase + (size_t)t * N1;
        float g = bf2f(rp[1024 + n]), br = bf2f(rp[n]), bi = bf2f(rp[512 + n]);
        float ar = (1.0f - g) * cr, ai = (1.0f - g) * ci;
        float nqr = ar * qr - ai * qi + g * br;
        float nqi = ar * qi + ai * qr + g * bi;
        float nPr = ar * Pr - ai * Pi;
        float nPi = ar * Pi + ai * Pr;
        qr = nqr; qi = nqi; Pr = nPr; Pi = nPi;
    }
    Pq[idx] = make_float4(Pr, Pi, qr, qi);
}

// phase 2: sequential chunk combine
__global__ __launch_bounds__(256) void scan2_kernel(
    const float4* __restrict__ Pq, const float* __restrict__ h0,
    float2* __restrict__ hin, float* __restrict__ hfin)
{
    int idx = blockIdx.x * 256 + threadIdx.x;      // < BATCH*SDIM
    int n = idx & (SDIM - 1);
    int b = idx >> 9;
    float hr = h0[idx * 2], hi = h0[idx * 2 + 1];
    for (int c = 0; c < SCH; ++c) {
        int o = (b * SCH + c) * SDIM + n;
        hin[o] = make_float2(hr, hi);
        float4 pq = Pq[o];
        float nr = pq.x * hr - pq.y * hi + pq.z;
        float ni = pq.x * hi + pq.y * hr + pq.w;
        hr = nr; hi = ni;
    }
    hfin[idx * 2] = hr;
    hfin[idx * 2 + 1] = hi;
}

// phase 3: replay chunks, write h_all bf16 [row][1024]
__global__ __launch_bounds__(256) void scan3_kernel(
    const unsigned short* __restrict__ g1o, const float* __restrict__ theta,
    const float* __restrict__ damp_p, const float2* __restrict__ hin,
    unsigned short* __restrict__ hall)
{
    int idx = blockIdx.x * 256 + threadIdx.x;      // < BATCH*SCH*SDIM
    int n = idx & (SDIM - 1);
    int c = (idx >> 9) & (SCH - 1);
    int b = idx >> (9 + SCH_LOG);
    float th = theta[n];
    float dp = 0.5f + 0.5f * (1.0f / (1.0f + expf(-damp_p[n])));
    float cr = dp * cosf(th), ci = dp * sinf(th);

    float2 h = hin[idx];
    float hr = h.x, hi = h.y;
    const unsigned short* rbase = g1o + ((size_t)b * SEQ + (size_t)c * SCL) * N1;
    unsigned short* hbase = hall + ((size_t)b * SEQ + (size_t)c * SCL) * K2;
#pragma unroll 4
    for (int t = 0; t < SCL; ++t) {
        const unsigned short* rp = rbase + (size_t)t * N1;
        float g = bf2f(rp[1024 + n]), br = bf2f(rp[n]), bi = bf2f(rp[512 + n]);
        float omg = 1.0f - g;
        float nr = g * br + omg * (hr * cr - hi * ci);
        float ni = g * bi + omg * (hr * ci + hi * cr);
        hr = nr; hi = ni;
        unsigned short* hb = hbase + (size_t)t * K2;
        hb[n] = f2bf(hr);
        hb[SDIM + n] = f2bf(hi);
    }
}

// ---------------------------------------------------------------------------
extern "C" void kernel_launch(void* const* d_in, const int* in_sizes, int n_in,
                              void* d_out, int out_size, void* d_ws, size_t ws_size,
                              hipStream_t stream)
{
    const float* x     = (const float*)d_in[0];
    const float* h0    = (const float*)d_in[1];
    const float* theta = (const float*)d_in[2];
    const float* dampp = (const float*)d_in[3];
    const float* BWr   = (const float*)d_in[4];
    const float* BWi   = (const float*)d_in[5];
    const float* CWr   = (const float*)d_in[6];
    const float* CWi   = (const float*)d_in[7];
    const float* DWr   = (const float*)d_in[8];
    const float* DWi   = (const float*)d_in[9];
    const float* gW    = (const float*)d_in[10];
    const float* gb    = (const float*)d_in[11];
    const float* ng    = (const float*)d_in[12];
    const float* nb    = (const float*)d_in[13];
    const float* og    = (const float*)d_in[14];
    const float* ob    = (const float*)d_in[15];
    float* out = (float*)d_out;

    char* ws = (char*)d_ws;
    float*          hbuf = (float*)ws;                       ws += (size_t)MROWS * DIM * 2 * 4;  // 16MB
    unsigned short* xnb  = (unsigned short*)ws;              ws += (size_t)MROWS * K1 * 2;       // 8MB
    unsigned short* g1o  = (unsigned short*)ws;              ws += (size_t)MROWS * N1 * 2;       // 32MB
    unsigned short* hall = (unsigned short*)ws;              ws += (size_t)MROWS * K2 * 2;       // 16MB
    unsigned short* W1t  = (unsigned short*)ws;              ws += (size_t)N1 * K1 * 2;          // 2MB
    unsigned short* W2t  = (unsigned short*)ws;              ws += (size_t)N2 * K2 * 2;          // 1MB
    float4*         Pq   = (float4*)ws;                      ws += (size_t)BATCH * SCH * SDIM * 16;
    float2*         hin  = (float2*)ws;                      ws += (size_t)BATCH * SCH * SDIM * 8;

    hipMemcpyAsync(hbuf, x, (size_t)MROWS * DIM * 2 * sizeof(float),
                   hipMemcpyDeviceToDevice, stream);

    for (int l = 0; l < NLAYERS; ++l) {
        ln_kernel<<<MROWS, 256, 0, stream>>>(hbuf, ng + l * DIM, nb + l * DIM,
                                             xnb, nullptr, 1);
        prep_w1t<<<dim3(64, 16), 256, 0, stream>>>(
            BWr + (size_t)l * DIM * SDIM, BWi + (size_t)l * DIM * SDIM,
            gW + (size_t)l * K1 * SDIM,
            DWr + (size_t)l * DIM * DIM, DWi + (size_t)l * DIM * DIM, W1t);
        prep_w2t<<<dim3(16, 32), 256, 0, stream>>>(
            CWr + (size_t)l * SDIM * DIM, CWi + (size_t)l * SDIM * DIM, W2t);

        mfma_gemm<0><<<dim3(N1 / 128, MROWS / 128), 256, 0, stream>>>(
            xnb, W1t, g1o, K1, gb + l * SDIM, nullptr, nullptr);

        scan1_kernel<<<(BATCH * SCH * SDIM) / 256, 256, 0, stream>>>(
            g1o, theta + l * SDIM, dampp + l * SDIM, Pq);
        scan2_kernel<<<(BATCH * SDIM) / 256, 256, 0, stream>>>(
            Pq, h0 + (size_t)l * BATCH * SDIM * 2, hin,
            out + (size_t)MROWS * DIM * 2 + (size_t)l * BATCH * SDIM * 2);
        scan3_kernel<<<(BATCH * SCH * SDIM) / 256, 256, 0, stream>>>(
            g1o, theta + l * SDIM, dampp + l * SDIM, hin, hall);

        mfma_gemm<1><<<dim3(N2 / 128, MROWS / 128), 256, 0, stream>>>(
            hall, W2t, nullptr, K2, nullptr, g1o, hbuf);
    }
    ln_kernel<<<MROWS, 256, 0, stream>>>(hbuf, og, ob, nullptr, out, 0);
}